// Round 9
// baseline (366.654 us; speedup 1.0000x reference)
//
#include <hip/hip_runtime.h>

#define B_DIM 4
#define C_DIM 512
#define N_DIM 4096
#define NS_F 4096.0f
#define LOG2E_F 1.4426950408889634f

typedef __attribute__((ext_vector_type(8))) short bf16x8;   // 8 bf16 = 4 VGPR
typedef __attribute__((ext_vector_type(4))) float f32x4;

__device__ __forceinline__ unsigned short f2bf(float f) {
    union { float f; unsigned int u; } a; a.f = f;
    unsigned int u = a.u;
    return (unsigned short)((u + 0x7fffu + ((u >> 16) & 1u)) >> 16);  // RNE
}
__device__ __forceinline__ float bf2f(unsigned short s) {
    union { unsigned int u; float f; } a; a.u = ((unsigned int)s) << 16;
    return a.f;
}

// ---------------------------------------------------------------------------
// wconv: W{q,k,v} fp32 -> bf16 concat [Wq | Wk | Wv] (same [o][c] layout)
// ---------------------------------------------------------------------------
__global__ __launch_bounds__(256) void wconv_kernel(
    const float* __restrict__ Wq, const float* __restrict__ Wk,
    const float* __restrict__ Wv, unsigned short* __restrict__ Wb)
{
    const int gid = blockIdx.x * 256 + threadIdx.x;
    const int flat = gid * 4;
    const float* src;
    if (flat < 32768)      src = Wq + flat;
    else if (flat < 65536) src = Wk + (flat - 32768);
    else                   src = Wv + (flat - 65536);
    float4 v = *(const float4*)src;
    ushort4 r;
    r.x = f2bf(v.x); r.y = f2bf(v.y); r.z = f2bf(v.z); r.w = f2bf(v.w);
    *(ushort4*)(Wb + flat) = r;
}

// ---------------------------------------------------------------------------
// xt: x[b][c][n] fp32 -> xT[b][n][c] bf16 via padded-LDS 64x64 transpose.
// ---------------------------------------------------------------------------
__global__ __launch_bounds__(256) void xt_kernel(
    const float* __restrict__ x, unsigned short* __restrict__ xT)
{
    const int b  = blockIdx.z;
    const int c0 = blockIdx.y * 64;
    const int n0 = blockIdx.x * 64;
    __shared__ float T[64][65];
    const int t   = threadIdx.x;
    const int l16 = t & 15;
    const int cr  = t >> 4;

    #pragma unroll
    for (int j = 0; j < 4; ++j) {
        const int c = cr + j * 16;
        float4 v = *(const float4*)(x + ((size_t)(b * C_DIM + c0 + c)) * N_DIM + n0 + l16 * 4);
        T[l16 * 4 + 0][c] = v.x;
        T[l16 * 4 + 1][c] = v.y;
        T[l16 * 4 + 2][c] = v.z;
        T[l16 * 4 + 3][c] = v.w;
    }
    __syncthreads();
    #pragma unroll
    for (int j = 0; j < 2; ++j) {
        const int chunk = t + j * 256;
        const int n  = chunk >> 3;
        const int c8 = (chunk & 7) * 8;
        bf16x8 r;
        #pragma unroll
        for (int e = 0; e < 8; ++e) r[e] = (short)f2bf(T[n][c8 + e]);
        *(bf16x8*)(xT + ((size_t)b * N_DIM + n0 + n) * 512 + c0 + c8) = r;
    }
}

// ---------------------------------------------------------------------------
// proj (MFMA, zero LDS, A-frags register-preloaded in 2 halves for deep ILP):
//   ot 0: qB[n][o]  = (xT.Wq^T + bq) * LOG2E  (exp2-domain logits)
//   ot 1: kB[n][o^swz]
//   ot 2..9: vB[c][n] = Wv.x + bv
// ---------------------------------------------------------------------------
__global__ __launch_bounds__(256, 2) void proj_kernel(
    const unsigned short* __restrict__ xT, const unsigned short* __restrict__ Wb,
    const float* __restrict__ bq, const float* __restrict__ bk,
    const float* __restrict__ bv,
    unsigned short* __restrict__ qB, unsigned short* __restrict__ kB,
    unsigned short* __restrict__ vB)
{
    const int ot = blockIdx.x;
    const int n0 = blockIdx.y * 64;
    const int b  = blockIdx.z;
    const int tid  = threadIdx.x;
    const int w    = tid >> 6;
    const int lane = tid & 63;
    const int lql  = lane & 15;
    const int lk4  = lane >> 4;

    f32x4 acc[4];
    #pragma unroll
    for (int og = 0; og < 4; ++og) acc[og] = (f32x4){0.f, 0.f, 0.f, 0.f};

    if (ot < 2) {
        const unsigned short* Wp = Wb + ot * 32768;
        const unsigned short* xa = xT + ((size_t)b * N_DIM + n0 + w * 16 + lql) * 512 + lk4 * 8;
        #pragma unroll
        for (int h = 0; h < 2; ++h) {
            bf16x8 af[8];
            #pragma unroll
            for (int i = 0; i < 8; ++i)
                af[i] = *(const bf16x8*)(xa + (h * 8 + i) * 32);
            #pragma unroll
            for (int i = 0; i < 8; ++i) {
                #pragma unroll
                for (int og = 0; og < 4; ++og) {
                    bf16x8 wf = *(const bf16x8*)(Wp + (size_t)(og * 16 + lql) * 512 + (h * 8 + i) * 32 + lk4 * 8);
                    acc[og] = __builtin_amdgcn_mfma_f32_16x16x32_bf16(af[i], wf, acc[og], 0, 0, 0);
                }
            }
        }
        const float* bias = (ot == 0) ? bq : bk;
        #pragma unroll
        for (int og = 0; og < 4; ++og) {
            const float bb = bias[og * 16 + lql];
            #pragma unroll
            for (int r = 0; r < 4; ++r) {
                const int n = n0 + w * 16 + lk4 * 4 + r;
                if (ot == 0) {
                    qB[((size_t)b * N_DIM + n) * 64 + og * 16 + lql] =
                        f2bf((acc[og][r] + bb) * LOG2E_F);
                } else {
                    const int o = og * 16 + lql;
                    kB[((size_t)b * N_DIM + n) * 64 + (o ^ ((n & 7) << 3))] =
                        f2bf(acc[og][r] + bb);
                }
            }
        }
    } else {
        const int cb0 = (ot - 2) * 64;
        const unsigned short* wa = Wb + 65536 + (size_t)(cb0 + w * 16 + lql) * 512 + lk4 * 8;
        const unsigned short* xb = xT + (size_t)b * N_DIM * 512;
        #pragma unroll
        for (int h = 0; h < 2; ++h) {
            bf16x8 af[8];
            #pragma unroll
            for (int i = 0; i < 8; ++i)
                af[i] = *(const bf16x8*)(wa + (h * 8 + i) * 32);
            #pragma unroll
            for (int i = 0; i < 8; ++i) {
                #pragma unroll
                for (int og = 0; og < 4; ++og) {
                    bf16x8 xf = *(const bf16x8*)(xb + (size_t)(n0 + og * 16 + lql) * 512 + (h * 8 + i) * 32 + lk4 * 8);
                    acc[og] = __builtin_amdgcn_mfma_f32_16x16x32_bf16(af[i], xf, acc[og], 0, 0, 0);
                }
            }
        }
        #pragma unroll
        for (int r = 0; r < 4; ++r) {
            const int c = cb0 + w * 16 + lk4 * 4 + r;
            const float bb = bv[c];
            #pragma unroll
            for (int og = 0; og < 4; ++og) {
                vB[((size_t)(b * C_DIM + c)) * N_DIM + n0 + og * 16 + lql] =
                    f2bf(acc[og][r] + bb);
            }
        }
    }
}

// ---------------------------------------------------------------------------
// flash (MFMA): grid 1024 = {4 b} x {64 m-tiles} x {4 c-quarters}, 256 thr.
// exp2-domain softmax (q pre-scaled by log2e). K stage: consecutive-16B/lane
// (conflict-free). P tile: stride 72 ushorts, no XOR (write 2-way-free,
// b128 read conflict-free). P pack via v_cvt_pk_bf16_f32.
// ---------------------------------------------------------------------------
__global__ __launch_bounds__(256, 4) void flash_kernel(
    const unsigned short* __restrict__ qB,
    const unsigned short* __restrict__ kB,
    const unsigned short* __restrict__ vB,
    const float* __restrict__ x,
    const float* __restrict__ gamma,
    float* __restrict__ stats,
    float* __restrict__ out)
{
    const int bid   = blockIdx.x;
    const int low3  = bid & 7;
    const int b     = low3 >> 1;
    const int c0bit = low3 & 1;
    const int high  = bid >> 3;
    const int mt    = high >> 1;
    const int ch    = ((high & 1) << 1) | c0bit;
    const int m0    = mt * 64;

    const int tid  = threadIdx.x;
    const int w    = tid >> 6;
    const int lane = tid & 63;
    const int lql  = lane & 15;
    const int lk4  = lane >> 4;
    const int swz  = (lql & 7) << 3;

    __shared__ __align__(16) unsigned short Kl[2][4096];   // [key][d] swizzled
    __shared__ __align__(16) unsigned short Pl[64][72];    // stride-72 pad
    __shared__ float scl[64];
    __shared__ float ll[64];
    __shared__ int   fl[4];

    const unsigned short* qrow = qB + ((size_t)b * N_DIM + m0 + w * 16 + lql) * 64 + lk4 * 8;
    const bf16x8 qf0 = *(const bf16x8*)(qrow);
    const bf16x8 qf1 = *(const bf16x8*)(qrow + 32);

    f32x4 acc[2][4];
    #pragma unroll
    for (int cg = 0; cg < 2; ++cg)
        #pragma unroll
        for (int qg = 0; qg < 4; ++qg)
            acc[cg][qg] = (f32x4){0.f, 0.f, 0.f, 0.f};

    float m_run = -3.0e38f;
    float l_run = 0.f;

    const unsigned short* kbb = kB + (size_t)b * N_DIM * 64;
    const unsigned short* vbb = vB + (size_t)b * C_DIM * N_DIM;
    const int cs = ch * 128 + w * 32;

    // K tile 0: each thread copies two consecutive-16B chunks (conflict-free)
    {
        bf16x8 a0 = *(const bf16x8*)(kbb + tid * 8);
        bf16x8 a1 = *(const bf16x8*)(kbb + 2048 + tid * 8);
        *(bf16x8*)(&Kl[0][tid * 8]) = a0;
        *(bf16x8*)(&Kl[0][2048 + tid * 8]) = a1;
    }
    __syncthreads();

    int buf = 0;
    for (int t = 0; t < 64; ++t) {
        const int tn_ = (t + 1) & 63;
        const bf16x8 kn0 = *(const bf16x8*)(kbb + (size_t)tn_ * 4096 + tid * 8);
        const bf16x8 kn1 = *(const bf16x8*)(kbb + (size_t)tn_ * 4096 + 2048 + tid * 8);

        // QK^T -> S^T (exp2-domain): rows = keys g*16+lk4*4+r, col = qrow = lql
        f32x4 s[4];
        #pragma unroll
        for (int g = 0; g < 4; ++g) {
            const unsigned short* kr = &Kl[buf][(g * 16 + lql) * 64];
            bf16x8 ka0 = *(const bf16x8*)(kr + ((lk4 * 8) ^ swz));
            bf16x8 ka1 = *(const bf16x8*)(kr + ((lk4 * 8 + 32) ^ swz));
            f32x4 z = (f32x4){0.f, 0.f, 0.f, 0.f};
            z = __builtin_amdgcn_mfma_f32_16x16x32_bf16(ka0, qf0, z, 0, 0, 0);
            z = __builtin_amdgcn_mfma_f32_16x16x32_bf16(ka1, qf1, z, 0, 0, 0);
            s[g] = z;
        }

        float pmax = s[0][0];
        #pragma unroll
        for (int g = 0; g < 4; ++g)
            #pragma unroll
            for (int r = 0; r < 4; ++r)
                pmax = fmaxf(pmax, s[g][r]);
        pmax = fmaxf(pmax, __shfl_xor(pmax, 16));
        pmax = fmaxf(pmax, __shfl_xor(pmax, 32));

        const int wflag = __any(pmax > m_run + 8.f);   // defer-max (exp2 units)
        float scv = 1.f;
        if (wflag) {
            const float nm = fmaxf(m_run, pmax);
            scv = exp2f(m_run - nm);
            m_run = nm;
        }
        float p[4][4];
        float ps = 0.f;
        #pragma unroll
        for (int g = 0; g < 4; ++g)
            #pragma unroll
            for (int r = 0; r < 4; ++r) {
                p[g][r] = exp2f(s[g][r] - m_run);
                ps += p[g][r];
            }
        ps += __shfl_xor(ps, 16);
        ps += __shfl_xor(ps, 32);
        l_run = l_run * scv + ps;

        if (lk4 == 0) scl[w * 16 + lql] = scv;
        if (lane == 0) fl[w] = wflag;

        // P -> LDS (cvt_pk packing; natural column order, stride-72 pad)
        {
            unsigned short* prow = &Pl[w * 16 + lql][0];
            #pragma unroll
            for (int g = 0; g < 4; ++g) {
                unsigned int lo, hi;
                asm("v_cvt_pk_bf16_f32 %0, %1, %2" : "=v"(lo) : "v"(p[g][0]), "v"(p[g][1]));
                asm("v_cvt_pk_bf16_f32 %0, %1, %2" : "=v"(hi) : "v"(p[g][2]), "v"(p[g][3]));
                *(uint2*)(prow + g * 16 + lk4 * 4) = make_uint2(lo, hi);
            }
        }
        __syncthreads();

        *(bf16x8*)(&Kl[buf ^ 1][tid * 8]) = kn0;
        *(bf16x8*)(&Kl[buf ^ 1][2048 + tid * 8]) = kn1;

        const int bflag = fl[0] | fl[1] | fl[2] | fl[3];
        if (bflag) {
            float sc4[4];
            #pragma unroll
            for (int qg = 0; qg < 4; ++qg) sc4[qg] = scl[qg * 16 + lql];
            #pragma unroll
            for (int cg = 0; cg < 2; ++cg)
                #pragma unroll
                for (int qg = 0; qg < 4; ++qg) {
                    acc[cg][qg][0] *= sc4[qg];
                    acc[cg][qg][1] *= sc4[qg];
                    acc[cg][qg][2] *= sc4[qg];
                    acc[cg][qg][3] *= sc4[qg];
                }
        }

        bf16x8 pf[4][2];
        #pragma unroll
        for (int qg = 0; qg < 4; ++qg) {
            const unsigned short* pr = &Pl[qg * 16 + lql][0];
            pf[qg][0] = *(const bf16x8*)(pr + lk4 * 8);
            pf[qg][1] = *(const bf16x8*)(pr + lk4 * 8 + 32);
        }

        const int n0 = t * 64;
        const unsigned short* vpb = vbb + (size_t)(cs + lql) * N_DIM + n0 + lk4 * 8;
        __builtin_amdgcn_s_setprio(1);
        #pragma unroll
        for (int cg = 0; cg < 2; ++cg) {
            const unsigned short* vp = vpb + (size_t)cg * 16 * N_DIM;
            bf16x8 va0 = *(const bf16x8*)(vp);
            bf16x8 va1 = *(const bf16x8*)(vp + 32);
            #pragma unroll
            for (int qg = 0; qg < 4; ++qg) {
                acc[cg][qg] = __builtin_amdgcn_mfma_f32_16x16x32_bf16(va0, pf[qg][0], acc[cg][qg], 0, 0, 0);
                acc[cg][qg] = __builtin_amdgcn_mfma_f32_16x16x32_bf16(va1, pf[qg][1], acc[cg][qg], 0, 0, 0);
            }
        }
        __builtin_amdgcn_s_setprio(0);
        __syncthreads();
        buf ^= 1;
    }

    if (mt == 0 && ch == 0 && tid == 0) {
        stats[b * 2 + 0] = m_run;
        stats[b * 2 + 1] = l_run;
    }

    if (lk4 == 0) ll[w * 16 + lql] = l_run;
    __syncthreads();

    const float gns = gamma[0] * NS_F;
    float inv4[4];
    #pragma unroll
    for (int qg = 0; qg < 4; ++qg) inv4[qg] = 1.f / ll[qg * 16 + lql];

    #pragma unroll
    for (int cg = 0; cg < 2; ++cg) {
        #pragma unroll
        for (int r = 0; r < 4; ++r) {
            const int c = cs + cg * 16 + lk4 * 4 + r;
            const size_t rowb = ((size_t)b * C_DIM + c) * N_DIM;
            #pragma unroll
            for (int qg = 0; qg < 4; ++qg) {
                const int mg = m0 + qg * 16 + lql;
                out[rowb + mg] = fmaf(gns * inv4[qg], acc[cg][qg][r], x[rowb + mg]);
            }
        }
    }
}

// ---------------------------------------------------------------------------
// patch: out[b][c][0] -= gamma * (NS * exp2(q0.k_s - m)/l) * v[c][s]
// (q0 is log2e-pre-scaled, so exp2 domain matches flash's stats.)
// ---------------------------------------------------------------------------
__global__ __launch_bounds__(512) void patch_kernel(
    const unsigned short* __restrict__ qB,
    const unsigned short* __restrict__ kB,
    const unsigned short* __restrict__ vB,
    const float* __restrict__ stats,
    const float* __restrict__ gamma,
    const int* __restrict__ sidx,
    float* __restrict__ out)
{
    const int b = blockIdx.x;
    const int c = threadIdx.x;
    __shared__ float q0s[64];
    if (c < 64) q0s[c] = bf2f(qB[(size_t)b * N_DIM * 64 + c]);
    __syncthreads();
    const int s  = sidx[b];
    const int m7 = s & 7;
    const unsigned short* kr = kB + ((size_t)b * N_DIM + s) * 64;
    float logit = 0.f;
    #pragma unroll
    for (int dj = 0; dj < 8; ++dj) {
        const int slot = dj ^ m7;
        bf16x8 kv = *(const bf16x8*)(kr + slot * 8);
        #pragma unroll
        for (int e = 0; e < 8; ++e)
            logit = fmaf(bf2f((unsigned short)kv[e]), q0s[dj * 8 + e], logit);
    }
    const float corr = NS_F * exp2f(logit - stats[b * 2]) / stats[b * 2 + 1];
    const float g = gamma[0];
    const float vcs = bf2f(vB[((size_t)b * C_DIM + c) * N_DIM + s]);
    out[((size_t)b * C_DIM + c) * N_DIM] -= g * corr * vcs;
}

// ---------------------------------------------------------------------------
extern "C" void kernel_launch(void* const* d_in, const int* in_sizes, int n_in,
                              void* d_out, int out_size, void* d_ws, size_t ws_size,
                              hipStream_t stream)
{
    const float* x     = (const float*)d_in[0];
    const float* Wq    = (const float*)d_in[1];
    const float* bq    = (const float*)d_in[2];
    const float* Wk    = (const float*)d_in[3];
    const float* bk    = (const float*)d_in[4];
    const float* Wv    = (const float*)d_in[5];
    const float* bv    = (const float*)d_in[6];
    const float* gamma = (const float*)d_in[7];
    const int*   sidx  = (const int*)d_in[8];
    float* out = (float*)d_out;

    // ws (ushorts): xT 8M | Wb 320K | qB 1M | kB 1M | vB 8M | stats (floats)
    unsigned short* xT = (unsigned short*)d_ws;
    unsigned short* Wb = xT + (size_t)B_DIM * N_DIM * 512;
    unsigned short* qB = Wb + 327680;
    unsigned short* kB = qB + (size_t)B_DIM * N_DIM * 64;
    unsigned short* vB = kB + (size_t)B_DIM * N_DIM * 64;
    float* stats = (float*)(vB + (size_t)B_DIM * C_DIM * N_DIM);

    wconv_kernel<<<dim3(320), 256, 0, stream>>>(Wq, Wk, Wv, Wb);
    xt_kernel<<<dim3(64, 8, B_DIM), 256, 0, stream>>>(x, xT);
    proj_kernel<<<dim3(10, 64, B_DIM), 256, 0, stream>>>(xT, Wb, bq, bk, bv, qB, kB, vB);
    flash_kernel<<<dim3(1024), 256, 0, stream>>>(qB, kB, vB, x, gamma, stats, out);
    patch_kernel<<<dim3(B_DIM), 512, 0, stream>>>(qB, kB, vB, stats, gamma, sidx, out);
}

// Round 10
// 316.052 us; speedup vs baseline: 1.1601x; 1.1601x over previous
//
#include <hip/hip_runtime.h>

#define B_DIM 4
#define C_DIM 512
#define N_DIM 4096
#define NS_F 4096.0f
#define LOG2E_F 1.4426950408889634f

typedef __attribute__((ext_vector_type(8))) short bf16x8;   // 8 bf16 = 4 VGPR
typedef __attribute__((ext_vector_type(4))) float f32x4;

__device__ __forceinline__ unsigned short f2bf(float f) {
    union { float f; unsigned int u; } a; a.f = f;
    unsigned int u = a.u;
    return (unsigned short)((u + 0x7fffu + ((u >> 16) & 1u)) >> 16);  // RNE
}
__device__ __forceinline__ float bf2f(unsigned short s) {
    union { unsigned int u; float f; } a; a.u = ((unsigned int)s) << 16;
    return a.f;
}

// ---------------------------------------------------------------------------
// wconv: W{q,k,v} fp32 -> bf16 concat [Wq | Wk | Wv] (same [o][c] layout)
// ---------------------------------------------------------------------------
__global__ __launch_bounds__(256) void wconv_kernel(
    const float* __restrict__ Wq, const float* __restrict__ Wk,
    const float* __restrict__ Wv, unsigned short* __restrict__ Wb)
{
    const int gid = blockIdx.x * 256 + threadIdx.x;
    const int flat = gid * 4;
    const float* src;
    if (flat < 32768)      src = Wq + flat;
    else if (flat < 65536) src = Wk + (flat - 32768);
    else                   src = Wv + (flat - 65536);
    float4 v = *(const float4*)src;
    ushort4 r;
    r.x = f2bf(v.x); r.y = f2bf(v.y); r.z = f2bf(v.z); r.w = f2bf(v.w);
    *(ushort4*)(Wb + flat) = r;
}

// ---------------------------------------------------------------------------
// xt: x[b][c][n] fp32 -> xT[b][n][c] bf16 via padded-LDS 64x64 transpose.
// ---------------------------------------------------------------------------
__global__ __launch_bounds__(256) void xt_kernel(
    const float* __restrict__ x, unsigned short* __restrict__ xT)
{
    const int b  = blockIdx.z;
    const int c0 = blockIdx.y * 64;
    const int n0 = blockIdx.x * 64;
    __shared__ float T[64][65];
    const int t   = threadIdx.x;
    const int l16 = t & 15;
    const int cr  = t >> 4;

    #pragma unroll
    for (int j = 0; j < 4; ++j) {
        const int c = cr + j * 16;
        float4 v = *(const float4*)(x + ((size_t)(b * C_DIM + c0 + c)) * N_DIM + n0 + l16 * 4);
        T[l16 * 4 + 0][c] = v.x;
        T[l16 * 4 + 1][c] = v.y;
        T[l16 * 4 + 2][c] = v.z;
        T[l16 * 4 + 3][c] = v.w;
    }
    __syncthreads();
    #pragma unroll
    for (int j = 0; j < 2; ++j) {
        const int chunk = t + j * 256;
        const int n  = chunk >> 3;
        const int c8 = (chunk & 7) * 8;
        bf16x8 r;
        #pragma unroll
        for (int e = 0; e < 8; ++e) r[e] = (short)f2bf(T[n][c8 + e]);
        *(bf16x8*)(xT + ((size_t)b * N_DIM + n0 + n) * 512 + c0 + c8) = r;
    }
}

// ---------------------------------------------------------------------------
// projf (fused MFMA proj): grid (64 n-slabs, 4 b), 256 thr = 4 waves.
// Stage the 64x512 bf16 xT slab in LDS ONCE (XOR-swizzled 16B chunks:
// chunk' = chunk ^ (n&7) -> all row-column reads are <=2-way bank aliased),
// then compute all 10 output slabs in-block:
//   ot0: qB[n][o] = (xs.Wq^T + bq)*LOG2E    (A = xs rows via ds_read_b128)
//   ot1: kB[n][o^swz]
//   vt0..7: vB[c][n] = Wv.xs + bv           (B = xs rows via ds_read_b128)
// Kills the 10x xT global re-read of the previous zero-LDS proj.
// ---------------------------------------------------------------------------
__global__ __launch_bounds__(256) void projf_kernel(
    const unsigned short* __restrict__ xT, const unsigned short* __restrict__ Wb,
    const float* __restrict__ bq, const float* __restrict__ bk,
    const float* __restrict__ bv,
    unsigned short* __restrict__ qB, unsigned short* __restrict__ kB,
    unsigned short* __restrict__ vB)
{
    const int n0 = blockIdx.x * 64;
    const int b  = blockIdx.y;
    const int tid  = threadIdx.x;
    const int w    = tid >> 6;
    const int lane = tid & 63;
    const int lql  = lane & 15;
    const int lk4  = lane >> 4;
    const int l7   = lql & 7;

    __shared__ __align__(16) unsigned short xs[64][512];

    // stage xT slab (coalesced global, swizzled LDS chunks)
    {
        const unsigned short* xTb = xT + (size_t)b * N_DIM * 512;
        #pragma unroll
        for (int j = 0; j < 16; ++j) {
            const int chunk = tid + j * 256;     // 0..4095
            const int n  = chunk >> 6;
            const int c8 = chunk & 63;
            bf16x8 v = *(const bf16x8*)(xTb + (size_t)(n0 + n) * 512 + c8 * 8);
            *(bf16x8*)(&xs[n][((c8 ^ (n & 7)) * 8)]) = v;
        }
    }
    __syncthreads();

    // ---- q and k projections: D[n][o], A = xs rows, B = W rows (L2) ----
    #pragma unroll
    for (int ot = 0; ot < 2; ++ot) {
        const unsigned short* Wp = Wb + ot * 32768;
        const int arow = w * 16 + lql;
        const int a7 = arow & 7;
        f32x4 acc[4];
        #pragma unroll
        for (int og = 0; og < 4; ++og) acc[og] = (f32x4){0.f, 0.f, 0.f, 0.f};
        #pragma unroll
        for (int ks = 0; ks < 16; ++ks) {
            bf16x8 a = *(const bf16x8*)(&xs[arow][((ks * 4 + lk4) ^ a7) * 8]);
            #pragma unroll
            for (int og = 0; og < 4; ++og) {
                bf16x8 wf = *(const bf16x8*)(Wp + (size_t)(og * 16 + lql) * 512 + ks * 32 + lk4 * 8);
                acc[og] = __builtin_amdgcn_mfma_f32_16x16x32_bf16(a, wf, acc[og], 0, 0, 0);
            }
        }
        const float* bias = (ot == 0) ? bq : bk;
        #pragma unroll
        for (int og = 0; og < 4; ++og) {
            const float bb = bias[og * 16 + lql];
            #pragma unroll
            for (int r = 0; r < 4; ++r) {
                const int n = n0 + w * 16 + lk4 * 4 + r;
                if (ot == 0) {
                    qB[((size_t)b * N_DIM + n) * 64 + og * 16 + lql] =
                        f2bf((acc[og][r] + bb) * LOG2E_F);
                } else {
                    const int o = og * 16 + lql;
                    kB[((size_t)b * N_DIM + n) * 64 + (o ^ ((n & 7) << 3))] =
                        f2bf(acc[og][r] + bb);
                }
            }
        }
    }

    // ---- v projection: D[c][n], A = Wv rows (L2), B = xs rows ----
    #pragma unroll
    for (int vt = 0; vt < 8; ++vt) {
        const int cb0 = vt * 64;
        const unsigned short* wa = Wb + 65536 + (size_t)(cb0 + w * 16 + lql) * 512 + lk4 * 8;
        f32x4 acc[4];
        #pragma unroll
        for (int og = 0; og < 4; ++og) acc[og] = (f32x4){0.f, 0.f, 0.f, 0.f};
        #pragma unroll
        for (int ks = 0; ks < 16; ++ks) {
            bf16x8 a = *(const bf16x8*)(wa + ks * 32);
            #pragma unroll
            for (int og = 0; og < 4; ++og) {
                const int brow = og * 16 + lql;
                bf16x8 xf = *(const bf16x8*)(&xs[brow][((ks * 4 + lk4) ^ l7) * 8]);
                acc[og] = __builtin_amdgcn_mfma_f32_16x16x32_bf16(a, xf, acc[og], 0, 0, 0);
            }
        }
        #pragma unroll
        for (int r = 0; r < 4; ++r) {
            const int c = cb0 + w * 16 + lk4 * 4 + r;
            const float bb = bv[c];
            #pragma unroll
            for (int og = 0; og < 4; ++og) {
                vB[((size_t)(b * C_DIM + c)) * N_DIM + n0 + og * 16 + lql] =
                    f2bf(acc[og][r] + bb);
            }
        }
    }
}

// ---------------------------------------------------------------------------
// flash (MFMA): REVERTED to the measured-180us r7 configuration
// (Pl stride-64 + XOR swizzle, scalar f2bf P-pack — m240: no inline cvt_pk),
// keeping two safe deltas: exp2-domain softmax (q pre-scaled by log2e) and
// contiguous-16B/lane K staging. grid 1024 = {4b} x {64 mt} x {4 c-quarters}.
// ---------------------------------------------------------------------------
__global__ __launch_bounds__(256, 4) void flash_kernel(
    const unsigned short* __restrict__ qB,
    const unsigned short* __restrict__ kB,
    const unsigned short* __restrict__ vB,
    const float* __restrict__ x,
    const float* __restrict__ gamma,
    float* __restrict__ stats,
    float* __restrict__ out)
{
    const int bid   = blockIdx.x;
    const int low3  = bid & 7;
    const int b     = low3 >> 1;
    const int c0bit = low3 & 1;
    const int high  = bid >> 3;
    const int mt    = high >> 1;
    const int ch    = ((high & 1) << 1) | c0bit;
    const int m0    = mt * 64;

    const int tid  = threadIdx.x;
    const int w    = tid >> 6;
    const int lane = tid & 63;
    const int lql  = lane & 15;
    const int lk4  = lane >> 4;
    const int swz  = (lql & 7) << 3;

    __shared__ __align__(16) unsigned short Kl[2][4096];   // [key][d] swizzled
    __shared__ __align__(16) unsigned short Pl[4096];      // [qrow][key] swizzled
    __shared__ float scl[64];
    __shared__ float ll[64];
    __shared__ int   fl[4];

    const unsigned short* qrow = qB + ((size_t)b * N_DIM + m0 + w * 16 + lql) * 64 + lk4 * 8;
    const bf16x8 qf0 = *(const bf16x8*)(qrow);
    const bf16x8 qf1 = *(const bf16x8*)(qrow + 32);

    f32x4 acc[2][4];
    #pragma unroll
    for (int cg = 0; cg < 2; ++cg)
        #pragma unroll
        for (int qg = 0; qg < 4; ++qg)
            acc[cg][qg] = (f32x4){0.f, 0.f, 0.f, 0.f};

    float m_run = -3.0e38f;
    float l_run = 0.f;

    const unsigned short* kbb = kB + (size_t)b * N_DIM * 64;
    const unsigned short* vbb = vB + (size_t)b * C_DIM * N_DIM;
    const int cs = ch * 128 + w * 32;

    // K tile 0: contiguous-16B/lane copy (conflict-free)
    {
        bf16x8 a0 = *(const bf16x8*)(kbb + tid * 8);
        bf16x8 a1 = *(const bf16x8*)(kbb + 2048 + tid * 8);
        *(bf16x8*)(&Kl[0][tid * 8]) = a0;
        *(bf16x8*)(&Kl[0][2048 + tid * 8]) = a1;
    }
    __syncthreads();

    int buf = 0;
    for (int t = 0; t < 64; ++t) {
        const int tn_ = (t + 1) & 63;
        const bf16x8 kn0 = *(const bf16x8*)(kbb + (size_t)tn_ * 4096 + tid * 8);
        const bf16x8 kn1 = *(const bf16x8*)(kbb + (size_t)tn_ * 4096 + 2048 + tid * 8);

        // QK^T -> S^T (exp2-domain): rows = keys g*16+lk4*4+r, col = qrow = lql
        f32x4 s[4];
        #pragma unroll
        for (int g = 0; g < 4; ++g) {
            const unsigned short* kr = &Kl[buf][(g * 16 + lql) * 64];
            bf16x8 ka0 = *(const bf16x8*)(kr + ((lk4 * 8) ^ swz));
            bf16x8 ka1 = *(const bf16x8*)(kr + ((lk4 * 8 + 32) ^ swz));
            f32x4 z = (f32x4){0.f, 0.f, 0.f, 0.f};
            z = __builtin_amdgcn_mfma_f32_16x16x32_bf16(ka0, qf0, z, 0, 0, 0);
            z = __builtin_amdgcn_mfma_f32_16x16x32_bf16(ka1, qf1, z, 0, 0, 0);
            s[g] = z;
        }

        float pmax = s[0][0];
        #pragma unroll
        for (int g = 0; g < 4; ++g)
            #pragma unroll
            for (int r = 0; r < 4; ++r)
                pmax = fmaxf(pmax, s[g][r]);
        pmax = fmaxf(pmax, __shfl_xor(pmax, 16));
        pmax = fmaxf(pmax, __shfl_xor(pmax, 32));

        const int wflag = __any(pmax > m_run + 8.f);   // defer-max THR=8
        float scv = 1.f;
        if (wflag) {
            const float nm = fmaxf(m_run, pmax);
            scv = exp2f(m_run - nm);
            m_run = nm;
        }
        float p[4][4];
        float ps = 0.f;
        #pragma unroll
        for (int g = 0; g < 4; ++g)
            #pragma unroll
            for (int r = 0; r < 4; ++r) {
                p[g][r] = exp2f(s[g][r] - m_run);
                ps += p[g][r];
            }
        ps += __shfl_xor(ps, 16);
        ps += __shfl_xor(ps, 32);
        l_run = l_run * scv + ps;

        if (lk4 == 0) scl[w * 16 + lql] = scv;
        if (lane == 0) fl[w] = wflag;

        // P -> LDS (scalar f2bf pack; stride-64 + XOR layout, r7-measured)
        {
            const int prow = (w * 16 + lql) * 64;
            #pragma unroll
            for (int g = 0; g < 4; ++g) {
                unsigned int lo = (unsigned int)f2bf(p[g][0]) | ((unsigned int)f2bf(p[g][1]) << 16);
                unsigned int hi = (unsigned int)f2bf(p[g][2]) | ((unsigned int)f2bf(p[g][3]) << 16);
                *(uint2*)(&Pl[prow + ((g * 16 + lk4 * 4) ^ swz)]) = make_uint2(lo, hi);
            }
        }
        __syncthreads();

        *(bf16x8*)(&Kl[buf ^ 1][tid * 8]) = kn0;
        *(bf16x8*)(&Kl[buf ^ 1][2048 + tid * 8]) = kn1;

        const int bflag = fl[0] | fl[1] | fl[2] | fl[3];
        if (bflag) {
            float sc4[4];
            #pragma unroll
            for (int qg = 0; qg < 4; ++qg) sc4[qg] = scl[qg * 16 + lql];
            #pragma unroll
            for (int cg = 0; cg < 2; ++cg)
                #pragma unroll
                for (int qg = 0; qg < 4; ++qg) {
                    acc[cg][qg][0] *= sc4[qg];
                    acc[cg][qg][1] *= sc4[qg];
                    acc[cg][qg][2] *= sc4[qg];
                    acc[cg][qg][3] *= sc4[qg];
                }
        }

        bf16x8 pf[4][2];
        #pragma unroll
        for (int qg = 0; qg < 4; ++qg) {
            const unsigned short* pr = &Pl[(qg * 16 + lql) * 64];
            pf[qg][0] = *(const bf16x8*)(pr + ((lk4 * 8) ^ swz));
            pf[qg][1] = *(const bf16x8*)(pr + ((lk4 * 8 + 32) ^ swz));
        }

        const int n0 = t * 64;
        const unsigned short* vpb = vbb + (size_t)(cs + lql) * N_DIM + n0 + lk4 * 8;
        __builtin_amdgcn_s_setprio(1);
        #pragma unroll
        for (int cg = 0; cg < 2; ++cg) {
            const unsigned short* vp = vpb + (size_t)cg * 16 * N_DIM;
            bf16x8 va0 = *(const bf16x8*)(vp);
            bf16x8 va1 = *(const bf16x8*)(vp + 32);
            #pragma unroll
            for (int qg = 0; qg < 4; ++qg) {
                acc[cg][qg] = __builtin_amdgcn_mfma_f32_16x16x32_bf16(va0, pf[qg][0], acc[cg][qg], 0, 0, 0);
                acc[cg][qg] = __builtin_amdgcn_mfma_f32_16x16x32_bf16(va1, pf[qg][1], acc[cg][qg], 0, 0, 0);
            }
        }
        __builtin_amdgcn_s_setprio(0);
        __syncthreads();
        buf ^= 1;
    }

    if (mt == 0 && ch == 0 && tid == 0) {
        stats[b * 2 + 0] = m_run;
        stats[b * 2 + 1] = l_run;
    }

    if (lk4 == 0) ll[w * 16 + lql] = l_run;
    __syncthreads();

    const float gns = gamma[0] * NS_F;
    float inv4[4];
    #pragma unroll
    for (int qg = 0; qg < 4; ++qg) inv4[qg] = 1.f / ll[qg * 16 + lql];

    #pragma unroll
    for (int cg = 0; cg < 2; ++cg) {
        #pragma unroll
        for (int r = 0; r < 4; ++r) {
            const int c = cs + cg * 16 + lk4 * 4 + r;
            const size_t rowb = ((size_t)b * C_DIM + c) * N_DIM;
            #pragma unroll
            for (int qg = 0; qg < 4; ++qg) {
                const int mg = m0 + qg * 16 + lql;
                out[rowb + mg] = fmaf(gns * inv4[qg], acc[cg][qg][r], x[rowb + mg]);
            }
        }
    }
}

// ---------------------------------------------------------------------------
// patch: out[b][c][0] -= gamma * (NS * exp2(q0.k_s - m)/l) * v[c][s]
// ---------------------------------------------------------------------------
__global__ __launch_bounds__(512) void patch_kernel(
    const unsigned short* __restrict__ qB,
    const unsigned short* __restrict__ kB,
    const unsigned short* __restrict__ vB,
    const float* __restrict__ stats,
    const float* __restrict__ gamma,
    const int* __restrict__ sidx,
    float* __restrict__ out)
{
    const int b = blockIdx.x;
    const int c = threadIdx.x;
    __shared__ float q0s[64];
    if (c < 64) q0s[c] = bf2f(qB[(size_t)b * N_DIM * 64 + c]);
    __syncthreads();
    const int s  = sidx[b];
    const int m7 = s & 7;
    const unsigned short* kr = kB + ((size_t)b * N_DIM + s) * 64;
    float logit = 0.f;
    #pragma unroll
    for (int dj = 0; dj < 8; ++dj) {
        const int slot = dj ^ m7;
        bf16x8 kv = *(const bf16x8*)(kr + slot * 8);
        #pragma unroll
        for (int e = 0; e < 8; ++e)
            logit = fmaf(bf2f((unsigned short)kv[e]), q0s[dj * 8 + e], logit);
    }
    const float corr = NS_F * exp2f(logit - stats[b * 2]) / stats[b * 2 + 1];
    const float g = gamma[0];
    const float vcs = bf2f(vB[((size_t)b * C_DIM + c) * N_DIM + s]);
    out[((size_t)b * C_DIM + c) * N_DIM] -= g * corr * vcs;
}

// ---------------------------------------------------------------------------
extern "C" void kernel_launch(void* const* d_in, const int* in_sizes, int n_in,
                              void* d_out, int out_size, void* d_ws, size_t ws_size,
                              hipStream_t stream)
{
    const float* x     = (const float*)d_in[0];
    const float* Wq    = (const float*)d_in[1];
    const float* bq    = (const float*)d_in[2];
    const float* Wk    = (const float*)d_in[3];
    const float* bk    = (const float*)d_in[4];
    const float* Wv    = (const float*)d_in[5];
    const float* bv    = (const float*)d_in[6];
    const float* gamma = (const float*)d_in[7];
    const int*   sidx  = (const int*)d_in[8];
    float* out = (float*)d_out;

    // ws (ushorts): xT 8M | Wb 320K | qB 1M | kB 1M | vB 8M | stats (floats)
    unsigned short* xT = (unsigned short*)d_ws;
    unsigned short* Wb = xT + (size_t)B_DIM * N_DIM * 512;
    unsigned short* qB = Wb + 327680;
    unsigned short* kB = qB + (size_t)B_DIM * N_DIM * 64;
    unsigned short* vB = kB + (size_t)B_DIM * N_DIM * 64;
    float* stats = (float*)(vB + (size_t)B_DIM * C_DIM * N_DIM);

    wconv_kernel<<<dim3(320), 256, 0, stream>>>(Wq, Wk, Wv, Wb);
    xt_kernel<<<dim3(64, 8, B_DIM), 256, 0, stream>>>(x, xT);
    projf_kernel<<<dim3(64, B_DIM), 256, 0, stream>>>(xT, Wb, bq, bk, bv, qB, kB, vB);
    flash_kernel<<<dim3(1024), 256, 0, stream>>>(qB, kB, vB, x, gamma, stats, out);
    patch_kernel<<<dim3(B_DIM), 512, 0, stream>>>(qB, kB, vB, stats, gamma, sidx, out);
}